// Round 5
// baseline (381.172 us; speedup 1.0000x reference)
//
#include <hip/hip_runtime.h>
#include <stdint.h>

// ---------- helpers ----------
typedef short v8s __attribute__((ext_vector_type(8)));
typedef float v4f __attribute__((ext_vector_type(4)));
typedef float v2f __attribute__((ext_vector_type(2)));

__device__ inline float bf2f(unsigned short h) {
    union { unsigned u; float f; } c; c.u = ((unsigned)h) << 16; return c.f;
}
__device__ inline unsigned short f2bf(float f) {
    union { float f; unsigned u; } c; c.f = f;
    unsigned u = c.u;
    unsigned r = (u + 0x7FFFu + ((u >> 16) & 1u)) >> 16;  // RNE
    return (unsigned short)r;
}
__device__ inline void gl_lds16(const unsigned short* g, unsigned short* l) {
    __builtin_amdgcn_global_load_lds(
        (const __attribute__((address_space(1))) unsigned int*)(g),
        (__attribute__((address_space(3))) unsigned int*)(l), 16, 0, 0);
}

// ---------- fused preprocessing pass 1 ----------
// blocks [0,gE): edge count + sequence number (atomic return value)
// blocks [gE,gE+gX): x fp32 -> bf16 padded
// blocks [gE+gX,...): W1/W2/W3 -> transposed bf16
__global__ void k_pre1(const int* __restrict__ dst, int E,
                       int* __restrict__ cnt, int* __restrict__ seq,
                       const float* __restrict__ x, unsigned short* __restrict__ A,
                       int n, int mpad,
                       const float* __restrict__ W1, const float* __restrict__ W2,
                       const float* __restrict__ W3, unsigned short* __restrict__ Wt,
                       int gE, int gX) {
    int b = blockIdx.x;
    if (b < gE) {
        int e = b * 256 + threadIdx.x;
        if (e < E) seq[e] = atomicAdd(&cnt[dst[e]], 1);
    } else if (b < gE + gX) {
        int g = (b - gE) * 256 + threadIdx.x;  // one float4 group
        int total = mpad * 64;
        if (g >= total) return;
        int row = g >> 6;
        float4 v;
        if (row < n) v = ((const float4*)x)[(size_t)g];
        else v = make_float4(0.f, 0.f, 0.f, 0.f);
        ushort4 o;
        o.x = f2bf(v.x); o.y = f2bf(v.y); o.z = f2bf(v.z); o.w = f2bf(v.w);
        ((ushort4*)A)[(size_t)g] = o;
    } else {
        int idx = (b - gE - gX) * 256 + threadIdx.x;  // < 163840 exact
        const float* W; int base, N;
        if (idx < 65536)       { W = W1; base = 0;      N = 256; }
        else if (idx < 131072) { W = W2; base = 65536;  N = 256; }
        else                   { W = W3; base = 131072; N = 128; }
        int loc = idx - base;
        int nn = loc >> 8;   // K = 256
        int k = loc & 255;
        Wt[idx] = f2bf(W[(size_t)k * N + nn]);
    }
}

// ---------- single-dispatch scan (fused scan1+scan2+scan3) ----------
// Each block redundantly sums cnt[0..base) (cnt is 200 KB -> L2-hot),
// then local inclusive scan; writes exclusive row-start rs and dinv.
__global__ void k_scan(const int* __restrict__ cnt, int n,
                       int* __restrict__ rs, float* __restrict__ dinv) {
    __shared__ int sm[256];
    __shared__ int preS;
    const int t = threadIdx.x;
    const int base = blockIdx.x * 256;

    int acc = 0;
    for (int j = t; j < base; j += 256) acc += cnt[j];
    sm[t] = acc; __syncthreads();
    for (int s = 128; s > 0; s >>= 1) {
        if (t < s) sm[t] += sm[t + s];
        __syncthreads();
    }
    if (t == 0) preS = sm[0];
    __syncthreads();

    const int i = base + t;
    const int v = (i < n) ? cnt[i] : 0;
    sm[t] = v; __syncthreads();
    for (int off = 1; off < 256; off <<= 1) {
        int a = (t >= off) ? sm[t - off] : 0;
        __syncthreads();
        sm[t] += a;
        __syncthreads();
    }
    if (i < n) {
        rs[i] = preS + sm[t] - v;           // exclusive start
        dinv[i] = rsqrtf((float)(v + 1));   // +1 self loop
    }
}

// ---------- GEMM body (round-3 proven best: single-buffer, 2-barrier) ----------
__device__ __forceinline__ void gemm_body(
        const unsigned short* __restrict__ A, const unsigned short* __restrict__ Wt,
        unsigned short* __restrict__ Hs, const float* __restrict__ dinv,
        int n, int N, int m0, int n0,
        unsigned short* sA, unsigned short* sB) {
    const int t = threadIdx.x;
    const int lane = t & 63;
    const int wave = t >> 6;
    const int wm = wave >> 1, wn = wave & 1;

    v4f acc[4][4];
#pragma unroll
    for (int i = 0; i < 4; i++)
#pragma unroll
        for (int j = 0; j < 4; j++)
#pragma unroll
            for (int r = 0; r < 4; r++) acc[i][j][r] = 0.f;

    const int c0 = t, c1 = t + 256;
    const int r0 = c0 >> 2, kc0 = (c0 & 3) * 8;
    const int r1 = c1 >> 2, kc1 = (c1 & 3) * 8;
    const size_t aBase0 = (size_t)(m0 + r0) * 256 + kc0;
    const size_t aBase1 = (size_t)(m0 + r1) * 256 + kc1;
    const size_t bBase0 = (size_t)(n0 + r0) * 256 + kc0;
    const size_t bBase1 = (size_t)(n0 + r1) * 256 + kc1;

    const int q = lane >> 4;
    const int lm = lane & 15;

    for (int k0 = 0; k0 < 256; k0 += 32) {
        __syncthreads();
        gl_lds16(A + aBase0 + k0, &sA[c0 * 8]);
        gl_lds16(A + aBase1 + k0, &sA[c1 * 8]);
        gl_lds16(Wt + bBase0 + k0, &sB[c0 * 8]);
        gl_lds16(Wt + bBase1 + k0, &sB[c1 * 8]);
        __syncthreads();

        v8s afr[4], bfr[4];
#pragma unroll
        for (int i = 0; i < 4; i++) {
            int r = wm * 64 + i * 16 + lm;
            afr[i] = *(const v8s*)&sA[r * 32 + q * 8];
        }
#pragma unroll
        for (int j = 0; j < 4; j++) {
            int nn = wn * 64 + j * 16 + lm;
            bfr[j] = *(const v8s*)&sB[nn * 32 + q * 8];
        }
#pragma unroll
        for (int i = 0; i < 4; i++)
#pragma unroll
            for (int j = 0; j < 4; j++)
                acc[i][j] = __builtin_amdgcn_mfma_f32_16x16x32_bf16(afr[i], bfr[j],
                                                                    acc[i][j], 0, 0, 0);
    }

    // epilogue: C/D layout col=lane&15, row=(lane>>4)*4+reg
#pragma unroll
    for (int i = 0; i < 4; i++) {
        int mbase = m0 + wm * 64 + i * 16 + q * 4;
#pragma unroll
        for (int r = 0; r < 4; r++) {
            int m = mbase + r;
            float s = (m < n) ? dinv[m] : 0.f;
#pragma unroll
            for (int j = 0; j < 4; j++) {
                int colI = n0 + wn * 64 + j * 16 + lm;
                Hs[(size_t)m * N + colI] = f2bf(acc[i][j][r] * s);
            }
        }
    }
}

__launch_bounds__(256, 4)
__global__ void k_gemm(const unsigned short* __restrict__ A,
                       const unsigned short* __restrict__ Wt,
                       unsigned short* __restrict__ Hs,
                       const float* __restrict__ dinv, int n, int N) {
    __shared__ unsigned short sA[128 * 32];
    __shared__ unsigned short sB[128 * 32];
    gemm_body(A, Wt, Hs, dinv, n, N, blockIdx.x * 128, blockIdx.y * 128, sA, sB);
}

// ---------- fused scatter + gemm1 ----------
// blocks [0, gemmBlocks): gemm1 tiles (MFMA-heavy); blocks beyond: edge scatter
// (pure-memory) backfills CUs and overlaps with the gemm's compute.
__launch_bounds__(256, 4)
__global__ void k_sg(const unsigned short* __restrict__ A,
                     const unsigned short* __restrict__ Wt,
                     unsigned short* __restrict__ Hs,
                     const float* __restrict__ dinv, int n, int N, int nmb,
                     const int* __restrict__ src, const int* __restrict__ dst,
                     const int* __restrict__ seq, int E,
                     const int* __restrict__ rs, int* __restrict__ col,
                     int gemmBlocks) {
    __shared__ unsigned short sA[128 * 32];
    __shared__ unsigned short sB[128 * 32];
    const int b = blockIdx.x;
    if (b >= gemmBlocks) {
        int e = (b - gemmBlocks) * 256 + threadIdx.x;
        if (e < E) col[rs[dst[e]] + seq[e]] = src[e];
        return;
    }
    const int bx = b % nmb, by = b / nmb;
    gemm_body(A, Wt, Hs, dinv, n, N, bx * 128, by * 128, sA, sB);
}

// ---------- aggregation: out[i] = act(dinv[i]*(sum_{nbr} hs[src] + hs[i]) + b) ----------
// (control group — random-gather memory-system ceiling; ILP-insensitive)
template <int D, bool RELU, bool F32OUT>
__launch_bounds__(256, 8)
__global__ void k_agg(const unsigned short* __restrict__ Hs,
                      const int* __restrict__ rs, const int* __restrict__ cnt,
                      const int* __restrict__ col, const float* __restrict__ dinv,
                      const float* __restrict__ bias,
                      unsigned short* __restrict__ outb, float* __restrict__ outf,
                      int n, int nzero) {
    constexpr int LPN = D / 8;     // lanes per neighbor row
    constexpr int NPG = 64 / LPN;  // neighbors per gather instruction
    const int lane = threadIdx.x & 63;
    const int i = blockIdx.x * 4 + (threadIdx.x >> 6);
    if (i >= n) return;
    const int g = lane / LPN;
    const int cl = lane % LPN;

    v2f acc[4];
#pragma unroll
    for (int k = 0; k < 4; k++) acc[k] = (v2f){0.f, 0.f};

    auto accq = [&](unsigned u, int k) {
        union { unsigned uu; float f; } lo, hi;
        lo.uu = u << 16;
        hi.uu = u & 0xffff0000u;
        v2f t; t[0] = lo.f; t[1] = hi.f;
        acc[k] += t;
    };
    auto acc16 = [&](uint4 q) { accq(q.x, 0); accq(q.y, 1); accq(q.z, 2); accq(q.w, 3); };

    const unsigned short* base = Hs + cl * 8;
    const int s = rs[i], deg = cnt[i];
    const int T = deg + 1;
    const int Tpad = (T + NPG - 1) & ~(NPG - 1);

    for (int b = 0; b < Tpad; b += 64) {
        int t = b + lane;
        int v;
        if (t == 0) v = i;
        else if (t <= deg) v = col[s + t - 1];
        else v = nzero;
        int lim = min(64, Tpad - b);
        int t2 = 0;
        for (; t2 + 4 * NPG <= lim; t2 += 4 * NPG) {
            int c0 = __shfl(v, t2 + 0 * NPG + g);
            int c1 = __shfl(v, t2 + 1 * NPG + g);
            int c2 = __shfl(v, t2 + 2 * NPG + g);
            int c3 = __shfl(v, t2 + 3 * NPG + g);
            uint4 q0 = *(const uint4*)(base + (size_t)c0 * D);
            uint4 q1 = *(const uint4*)(base + (size_t)c1 * D);
            uint4 q2 = *(const uint4*)(base + (size_t)c2 * D);
            uint4 q3 = *(const uint4*)(base + (size_t)c3 * D);
            acc16(q0); acc16(q1); acc16(q2); acc16(q3);
        }
        for (; t2 + NPG <= lim; t2 += NPG) {
            int c0 = __shfl(v, t2 + g);
            uint4 q0 = *(const uint4*)(base + (size_t)c0 * D);
            acc16(q0);
        }
    }

#pragma unroll
    for (int off = LPN; off < 64; off <<= 1) {
#pragma unroll
        for (int k = 0; k < 4; k++) {
            acc[k][0] += __shfl_xor(acc[k][0], off);
            acc[k][1] += __shfl_xor(acc[k][1], off);
        }
    }

    if (g == 0) {
        float di = dinv[i];
        float o[8];
#pragma unroll
        for (int k = 0; k < 4; k++) {
            o[2 * k + 0] = di * acc[k][0] + bias[cl * 8 + 2 * k + 0];
            o[2 * k + 1] = di * acc[k][1] + bias[cl * 8 + 2 * k + 1];
        }
        if (RELU) {
#pragma unroll
            for (int k = 0; k < 8; k++) o[k] = fmaxf(o[k], 0.f);
        }
        if constexpr (F32OUT) {
            float* p = outf + (size_t)i * D + cl * 8;
            *(float4*)p = make_float4(o[0], o[1], o[2], o[3]);
            *(float4*)(p + 4) = make_float4(o[4], o[5], o[6], o[7]);
        } else {
            uint4 q;
            q.x = ((unsigned)f2bf(o[1]) << 16) | f2bf(o[0]);
            q.y = ((unsigned)f2bf(o[3]) << 16) | f2bf(o[2]);
            q.z = ((unsigned)f2bf(o[5]) << 16) | f2bf(o[4]);
            q.w = ((unsigned)f2bf(o[7]) << 16) | f2bf(o[6]);
            *(uint4*)(outb + (size_t)i * D + cl * 8) = q;
        }
    }
}

// ---------- launch ----------
extern "C" void kernel_launch(void* const* d_in, const int* in_sizes, int n_in,
                              void* d_out, int out_size, void* d_ws, size_t ws_size,
                              hipStream_t stream) {
    const float* x  = (const float*)d_in[0];
    const int*   ei = (const int*)d_in[1];   // [2, E] int32
    const float* W1 = (const float*)d_in[2];
    const float* b1 = (const float*)d_in[3];
    const float* W2 = (const float*)d_in[4];
    const float* b2 = (const float*)d_in[5];
    const float* W3 = (const float*)d_in[6];
    const float* b3 = (const float*)d_in[7];

    const int n = in_sizes[0] / 256;     // 50000
    const int E = in_sizes[1] / 2;       // 800000
    const int mpad = ((n + 127) / 128) * 128;  // 50048

    char* ws = (char*)d_ws;
    size_t off = 0;
    auto alloc = [&](size_t bytes) -> void* {
        void* p = ws + off;
        off += (bytes + 511) & ~(size_t)511;  // 512B-aligned rows
        return p;
    };
    int* cnt      = (int*)alloc((size_t)n * 4);
    int* rs       = (int*)alloc((size_t)n * 4);
    float* dinv   = (float*)alloc((size_t)n * 4);
    int* seq      = (int*)alloc((size_t)E * 4);
    int* col      = (int*)alloc((size_t)E * 4);
    unsigned short* Wt = (unsigned short*)alloc((size_t)163840 * 2);
    unsigned short* W1t = Wt;
    unsigned short* W2t = Wt + 65536;
    unsigned short* W3t = Wt + 131072;
    unsigned short* bufA = (unsigned short*)alloc((size_t)mpad * 256 * 2);
    unsigned short* bufB = (unsigned short*)alloc((size_t)mpad * 256 * 2);
    (void)ws_size; (void)n_in; (void)out_size;

    const int* srcp = ei;
    const int* dstp = ei + E;
    const int gE = (E + 255) / 256;            // 3125
    const int gN = (n + 255) / 256;            // 196
    const int gX = (mpad * 64 + 255) / 256;    // 12512
    const int gW = 640;                        // 163840 / 256
    const int nmb = mpad / 128;                // 391

    hipMemsetAsync(cnt, 0, (size_t)n * 4, stream);

    k_pre1<<<gE + gX + gW, 256, 0, stream>>>(dstp, E, cnt, seq, x, bufA, n, mpad,
                                             W1, W2, W3, Wt, gE, gX);
    k_scan<<<gN, 256, 0, stream>>>(cnt, n, rs, dinv);

    // gemm1 + scatter fused (independent; overlap MFMA with scatter's memory)
    const int gemmBlocks = nmb * 2;            // N=256 -> 2 n-tiles
    k_sg<<<gemmBlocks + gE, 256, 0, stream>>>(bufA, W1t, bufB, dinv, n, 256, nmb,
                                              srcp, dstp, seq, E, rs, col, gemmBlocks);

    const int gAgg = (n + 3) / 4;
    k_agg<256, true, false><<<gAgg, 256, 0, stream>>>(bufB, rs, cnt, col, dinv, b1,
                                                      bufA, nullptr, n, n);
    dim3 gg2(nmb, 2);
    k_gemm<<<gg2, 256, 0, stream>>>(bufA, W2t, bufB, dinv, n, 256);
    k_agg<256, true, false><<<gAgg, 256, 0, stream>>>(bufB, rs, cnt, col, dinv, b2,
                                                      bufA, nullptr, n, n);
    dim3 gg3(nmb, 1);
    k_gemm<<<gg3, 256, 0, stream>>>(bufA, W3t, bufB, dinv, n, 128);
    k_agg<128, false, true><<<gAgg, 256, 0, stream>>>(bufB, rs, cnt, col, dinv, b3,
                                                      nullptr, (float*)d_out, n, n);
}

// Round 6
// 361.753 us; speedup vs baseline: 1.0537x; 1.0537x over previous
//
#include <hip/hip_runtime.h>
#include <stdint.h>

// ---------- helpers ----------
typedef short v8s __attribute__((ext_vector_type(8)));
typedef float v4f __attribute__((ext_vector_type(4)));
typedef float v2f __attribute__((ext_vector_type(2)));

__device__ inline float bf2f(unsigned short h) {
    union { unsigned u; float f; } c; c.u = ((unsigned)h) << 16; return c.f;
}
__device__ inline unsigned short f2bf(float f) {
    union { float f; unsigned u; } c; c.f = f;
    unsigned u = c.u;
    unsigned r = (u + 0x7FFFu + ((u >> 16) & 1u)) >> 16;  // RNE
    return (unsigned short)r;
}
__device__ inline void gl_lds16(const unsigned short* g, unsigned short* l) {
    __builtin_amdgcn_global_load_lds(
        (const __attribute__((address_space(1))) unsigned int*)(g),
        (__attribute__((address_space(3))) unsigned int*)(l), 16, 0, 0);
}

// ---------- fused preprocessing pass 1 ----------
// blocks [0,gE): edge count + sequence number (atomic return value)
// blocks [gE,gE+gX): x fp32 -> bf16 padded
// blocks [gE+gX,...): W1/W2/W3 -> transposed bf16
__global__ void k_pre1(const int* __restrict__ dst, int E,
                       int* __restrict__ cnt, int* __restrict__ seq,
                       const float* __restrict__ x, unsigned short* __restrict__ A,
                       int n, int mpad,
                       const float* __restrict__ W1, const float* __restrict__ W2,
                       const float* __restrict__ W3, unsigned short* __restrict__ Wt,
                       int gE, int gX) {
    int b = blockIdx.x;
    if (b < gE) {
        int e = b * 256 + threadIdx.x;
        if (e < E) seq[e] = atomicAdd(&cnt[dst[e]], 1);
    } else if (b < gE + gX) {
        int g = (b - gE) * 256 + threadIdx.x;  // one float4 group
        int total = mpad * 64;
        if (g >= total) return;
        int row = g >> 6;
        float4 v;
        if (row < n) v = ((const float4*)x)[(size_t)g];
        else v = make_float4(0.f, 0.f, 0.f, 0.f);
        ushort4 o;
        o.x = f2bf(v.x); o.y = f2bf(v.y); o.z = f2bf(v.z); o.w = f2bf(v.w);
        ((ushort4*)A)[(size_t)g] = o;
    } else {
        int idx = (b - gE - gX) * 256 + threadIdx.x;  // < 163840 exact
        const float* W; int base, N;
        if (idx < 65536)       { W = W1; base = 0;      N = 256; }
        else if (idx < 131072) { W = W2; base = 65536;  N = 256; }
        else                   { W = W3; base = 131072; N = 128; }
        int loc = idx - base;
        int nn = loc >> 8;   // K = 256
        int k = loc & 255;
        Wt[idx] = f2bf(W[(size_t)k * N + nn]);
    }
}

// ---------- scans ----------
__global__ void k_scan1(const int* __restrict__ cnt, int n, int* __restrict__ incl,
                        int* __restrict__ bsum) {
    __shared__ int sm[256];
    int t = threadIdx.x;
    int i = blockIdx.x * 256 + t;
    int v = (i < n) ? cnt[i] : 0;
    sm[t] = v; __syncthreads();
    for (int off = 1; off < 256; off <<= 1) {
        int add = (t >= off) ? sm[t - off] : 0;
        __syncthreads();
        sm[t] += add;
        __syncthreads();
    }
    if (i < n) incl[i] = sm[t];
    if (t == 255) bsum[blockIdx.x] = sm[255];
}

// fused scan2+scan3: each block computes its exclusive bsum prefix locally,
// then converts inclusive->exclusive global scan; also computes dinv.
__global__ void k_scan23(const int* __restrict__ cnt, int n,
                         const int* __restrict__ bsum,
                         int* __restrict__ rs, float* __restrict__ dinv) {
    __shared__ int red[256];
    int t = threadIdx.x;
    int acc = 0;
    for (int j = t; j < (int)blockIdx.x; j += 256) acc += bsum[j];
    red[t] = acc; __syncthreads();
    for (int s = 128; s > 0; s >>= 1) {
        if (t < s) red[t] += red[t + s];
        __syncthreads();
    }
    int boff = red[0];
    int i = blockIdx.x * 256 + t;
    if (i < n) {
        int c = cnt[i];
        rs[i] = rs[i] + boff - c;
        dinv[i] = rsqrtf((float)(c + 1));  // +1 self loop
    }
}

// ---------- scatter (atomic-free; position = rs[dst] + seq) ----------
__global__ void k_scatter2(const int* __restrict__ src, const int* __restrict__ dst,
                           const int* __restrict__ seq, int E,
                           const int* __restrict__ rs, int* __restrict__ col) {
    int e = blockIdx.x * 256 + threadIdx.x;
    if (e < E) col[rs[dst[e]] + seq[e]] = src[e];
}

// ---------- GEMM: Hs[m,n] = dinv[m] * sum_k A[m,k] * W[k,n] ----------
// 64x128 tile: 2x the blocks of the 128-tile version (gemm1/2: 1564, gemm3: 782)
// to fill co-residency slots; LDS 12 KB + acc 32 VGPR -> lb(256,6) = 6 blocks/CU
// (24 waves/CU) for latency hiding of the short (8-iter) barrier-bound K-loop.
// Wave w covers n-slice [wn*32, wn*32+32), all 64 m-rows.
__launch_bounds__(256, 6)
__global__ void k_gemm(const unsigned short* __restrict__ A,
                       const unsigned short* __restrict__ Wt,
                       unsigned short* __restrict__ Hs,
                       const float* __restrict__ dinv, int n, int N) {
    __shared__ unsigned short sA[64 * 32];    // 4 KB
    __shared__ unsigned short sB[128 * 32];   // 8 KB
    const int t = threadIdx.x;
    const int lane = t & 63;
    const int wn = t >> 6;                    // wave id = n-slice
    const int m0 = blockIdx.x * 64;
    const int n0 = blockIdx.y * 128;

    v4f acc[4][2];
#pragma unroll
    for (int i = 0; i < 4; i++)
#pragma unroll
        for (int j = 0; j < 2; j++)
#pragma unroll
            for (int r = 0; r < 4; r++) acc[i][j][r] = 0.f;

    // staging: A tile 64x32 = 256 chunks of 16B (1/thread);
    //          B tile 128x32 = 512 chunks (2/thread)
    const int c0 = t, c1 = t + 256;
    const int rA = c0 >> 2, kA = (c0 & 3) * 8;
    const int rB0 = c0 >> 2, kB0 = (c0 & 3) * 8;
    const int rB1 = c1 >> 2, kB1 = (c1 & 3) * 8;
    const size_t aBase  = (size_t)(m0 + rA) * 256 + kA;
    const size_t bBase0 = (size_t)(n0 + rB0) * 256 + kB0;
    const size_t bBase1 = (size_t)(n0 + rB1) * 256 + kB1;

    const int q = lane >> 4;
    const int lm = lane & 15;

    for (int k0 = 0; k0 < 256; k0 += 32) {
        __syncthreads();
        gl_lds16(A + aBase + k0, &sA[c0 * 8]);
        gl_lds16(Wt + bBase0 + k0, &sB[c0 * 8]);
        gl_lds16(Wt + bBase1 + k0, &sB[c1 * 8]);
        __syncthreads();

        v8s afr[4], bfr[2];
#pragma unroll
        for (int i = 0; i < 4; i++)
            afr[i] = *(const v8s*)&sA[(i * 16 + lm) * 32 + q * 8];
#pragma unroll
        for (int j = 0; j < 2; j++)
            bfr[j] = *(const v8s*)&sB[(wn * 32 + j * 16 + lm) * 32 + q * 8];
#pragma unroll
        for (int i = 0; i < 4; i++)
#pragma unroll
            for (int j = 0; j < 2; j++)
                acc[i][j] = __builtin_amdgcn_mfma_f32_16x16x32_bf16(afr[i], bfr[j],
                                                                    acc[i][j], 0, 0, 0);
    }

    // epilogue: C/D layout col=lane&15, row=(lane>>4)*4+reg
#pragma unroll
    for (int i = 0; i < 4; i++) {
        int mbase = m0 + i * 16 + q * 4;
#pragma unroll
        for (int r = 0; r < 4; r++) {
            int m = mbase + r;
            float s = (m < n) ? dinv[m] : 0.f;
#pragma unroll
            for (int j = 0; j < 2; j++) {
                int colI = n0 + wn * 32 + j * 16 + lm;
                Hs[(size_t)m * N + colI] = f2bf(acc[i][j][r] * s);
            }
        }
    }
}

// ---------- aggregation: out[i] = act(dinv[i]*(sum_{nbr} hs[src] + hs[i]) + b) ----------
// (control group — random-gather memory-system ceiling; ILP-insensitive)
template <int D, bool RELU, bool F32OUT>
__launch_bounds__(256, 8)
__global__ void k_agg(const unsigned short* __restrict__ Hs,
                      const int* __restrict__ rs, const int* __restrict__ cnt,
                      const int* __restrict__ col, const float* __restrict__ dinv,
                      const float* __restrict__ bias,
                      unsigned short* __restrict__ outb, float* __restrict__ outf,
                      int n, int nzero) {
    constexpr int LPN = D / 8;     // lanes per neighbor row
    constexpr int NPG = 64 / LPN;  // neighbors per gather instruction
    const int lane = threadIdx.x & 63;
    const int i = blockIdx.x * 4 + (threadIdx.x >> 6);
    if (i >= n) return;
    const int g = lane / LPN;
    const int cl = lane % LPN;

    v2f acc[4];
#pragma unroll
    for (int k = 0; k < 4; k++) acc[k] = (v2f){0.f, 0.f};

    auto accq = [&](unsigned u, int k) {
        union { unsigned uu; float f; } lo, hi;
        lo.uu = u << 16;
        hi.uu = u & 0xffff0000u;
        v2f t; t[0] = lo.f; t[1] = hi.f;
        acc[k] += t;
    };
    auto acc16 = [&](uint4 q) { accq(q.x, 0); accq(q.y, 1); accq(q.z, 2); accq(q.w, 3); };

    const unsigned short* base = Hs + cl * 8;
    const int s = rs[i], deg = cnt[i];
    const int T = deg + 1;
    const int Tpad = (T + NPG - 1) & ~(NPG - 1);

    for (int b = 0; b < Tpad; b += 64) {
        int t = b + lane;
        int v;
        if (t == 0) v = i;
        else if (t <= deg) v = col[s + t - 1];
        else v = nzero;
        int lim = min(64, Tpad - b);
        int t2 = 0;
        for (; t2 + 4 * NPG <= lim; t2 += 4 * NPG) {
            int c0 = __shfl(v, t2 + 0 * NPG + g);
            int c1 = __shfl(v, t2 + 1 * NPG + g);
            int c2 = __shfl(v, t2 + 2 * NPG + g);
            int c3 = __shfl(v, t2 + 3 * NPG + g);
            uint4 q0 = *(const uint4*)(base + (size_t)c0 * D);
            uint4 q1 = *(const uint4*)(base + (size_t)c1 * D);
            uint4 q2 = *(const uint4*)(base + (size_t)c2 * D);
            uint4 q3 = *(const uint4*)(base + (size_t)c3 * D);
            acc16(q0); acc16(q1); acc16(q2); acc16(q3);
        }
        for (; t2 + NPG <= lim; t2 += NPG) {
            int c0 = __shfl(v, t2 + g);
            uint4 q0 = *(const uint4*)(base + (size_t)c0 * D);
            acc16(q0);
        }
    }

#pragma unroll
    for (int off = LPN; off < 64; off <<= 1) {
#pragma unroll
        for (int k = 0; k < 4; k++) {
            acc[k][0] += __shfl_xor(acc[k][0], off);
            acc[k][1] += __shfl_xor(acc[k][1], off);
        }
    }

    if (g == 0) {
        float di = dinv[i];
        float o[8];
#pragma unroll
        for (int k = 0; k < 4; k++) {
            o[2 * k + 0] = di * acc[k][0] + bias[cl * 8 + 2 * k + 0];
            o[2 * k + 1] = di * acc[k][1] + bias[cl * 8 + 2 * k + 1];
        }
        if (RELU) {
#pragma unroll
            for (int k = 0; k < 8; k++) o[k] = fmaxf(o[k], 0.f);
        }
        if constexpr (F32OUT) {
            float* p = outf + (size_t)i * D + cl * 8;
            *(float4*)p = make_float4(o[0], o[1], o[2], o[3]);
            *(float4*)(p + 4) = make_float4(o[4], o[5], o[6], o[7]);
        } else {
            uint4 q;
            q.x = ((unsigned)f2bf(o[1]) << 16) | f2bf(o[0]);
            q.y = ((unsigned)f2bf(o[3]) << 16) | f2bf(o[2]);
            q.z = ((unsigned)f2bf(o[5]) << 16) | f2bf(o[4]);
            q.w = ((unsigned)f2bf(o[7]) << 16) | f2bf(o[6]);
            *(uint4*)(outb + (size_t)i * D + cl * 8) = q;
        }
    }
}

// ---------- launch ----------
extern "C" void kernel_launch(void* const* d_in, const int* in_sizes, int n_in,
                              void* d_out, int out_size, void* d_ws, size_t ws_size,
                              hipStream_t stream) {
    const float* x  = (const float*)d_in[0];
    const int*   ei = (const int*)d_in[1];   // [2, E] int32
    const float* W1 = (const float*)d_in[2];
    const float* b1 = (const float*)d_in[3];
    const float* W2 = (const float*)d_in[4];
    const float* b2 = (const float*)d_in[5];
    const float* W3 = (const float*)d_in[6];
    const float* b3 = (const float*)d_in[7];

    const int n = in_sizes[0] / 256;     // 50000
    const int E = in_sizes[1] / 2;       // 800000
    const int mpad = ((n + 127) / 128) * 128;  // 50048

    char* ws = (char*)d_ws;
    size_t off = 0;
    auto alloc = [&](size_t bytes) -> void* {
        void* p = ws + off;
        off += (bytes + 255) & ~(size_t)255;
        return p;
    };
    int* cnt      = (int*)alloc((size_t)n * 4);
    int* rs       = (int*)alloc((size_t)n * 4);
    float* dinv   = (float*)alloc((size_t)n * 4);
    int* bsum     = (int*)alloc(256 * 4);
    int* seq      = (int*)alloc((size_t)E * 4);
    int* col      = (int*)alloc((size_t)E * 4);
    unsigned short* Wt = (unsigned short*)alloc((size_t)163840 * 2);
    unsigned short* W1t = Wt;
    unsigned short* W2t = Wt + 65536;
    unsigned short* W3t = Wt + 131072;
    unsigned short* bufA = (unsigned short*)alloc((size_t)mpad * 256 * 2);
    unsigned short* bufB = (unsigned short*)alloc((size_t)mpad * 256 * 2);
    (void)ws_size; (void)n_in; (void)out_size;

    const int* srcp = ei;
    const int* dstp = ei + E;
    const int gE = (E + 255) / 256;            // 3125
    const int gN = (n + 255) / 256;            // 196
    const int gX = (mpad * 64 + 255) / 256;    // 12512
    const int gW = 640;                        // 163840 / 256

    hipMemsetAsync(cnt, 0, (size_t)n * 4, stream);

    k_pre1<<<gE + gX + gW, 256, 0, stream>>>(dstp, E, cnt, seq, x, bufA, n, mpad,
                                             W1, W2, W3, Wt, gE, gX);
    k_scan1<<<gN, 256, 0, stream>>>(cnt, n, rs, bsum);
    k_scan23<<<gN, 256, 0, stream>>>(cnt, n, bsum, rs, dinv);
    k_scatter2<<<gE, 256, 0, stream>>>(srcp, dstp, seq, E, rs, col);

    const int gAgg = (n + 3) / 4;
    const int nmb64 = mpad / 64;               // 782
    dim3 gg1(nmb64, 2);
    k_gemm<<<gg1, 256, 0, stream>>>(bufA, W1t, bufB, dinv, n, 256);
    k_agg<256, true, false><<<gAgg, 256, 0, stream>>>(bufB, rs, cnt, col, dinv, b1,
                                                      bufA, nullptr, n, n);
    k_gemm<<<gg1, 256, 0, stream>>>(bufA, W2t, bufB, dinv, n, 256);
    k_agg<256, true, false><<<gAgg, 256, 0, stream>>>(bufB, rs, cnt, col, dinv, b2,
                                                      bufA, nullptr, n, n);
    dim3 gg3(nmb64, 1);
    k_gemm<<<gg3, 256, 0, stream>>>(bufA, W3t, bufB, dinv, n, 128);
    k_agg<128, false, true><<<gAgg, 256, 0, stream>>>(bufB, rs, cnt, col, dinv, b3,
                                                      nullptr, (float*)d_out, n, n);
}

// Round 7
// 356.076 us; speedup vs baseline: 1.0705x; 1.0159x over previous
//
#include <hip/hip_runtime.h>
#include <stdint.h>

// ---------- helpers ----------
typedef short v8s __attribute__((ext_vector_type(8)));
typedef float v4f __attribute__((ext_vector_type(4)));
typedef float v2f __attribute__((ext_vector_type(2)));

__device__ inline float bf2f(unsigned short h) {
    union { unsigned u; float f; } c; c.u = ((unsigned)h) << 16; return c.f;
}
__device__ inline unsigned short f2bf(float f) {
    union { float f; unsigned u; } c; c.f = f;
    unsigned u = c.u;
    unsigned r = (u + 0x7FFFu + ((u >> 16) & 1u)) >> 16;  // RNE
    return (unsigned short)r;
}
__device__ inline void gl_lds16(const unsigned short* g, unsigned short* l) {
    __builtin_amdgcn_global_load_lds(
        (const __attribute__((address_space(1))) unsigned int*)(g),
        (__attribute__((address_space(3))) unsigned int*)(l), 16, 0, 0);
}

// ---------- preprocessing pass 1 ----------
// blocks [0,gE): edge count + sequence number (atomic return value)
// blocks [gE,...): W1/W2/W3 -> transposed bf16
__global__ void k_pre1(const int* __restrict__ dst, int E,
                       int* __restrict__ cnt, int* __restrict__ seq,
                       const float* __restrict__ W1, const float* __restrict__ W2,
                       const float* __restrict__ W3, unsigned short* __restrict__ Wt,
                       int gE) {
    int b = blockIdx.x;
    if (b < gE) {
        int e = b * 256 + threadIdx.x;
        if (e < E) seq[e] = atomicAdd(&cnt[dst[e]], 1);
    } else {
        int idx = (b - gE) * 256 + threadIdx.x;  // < 163840 exact
        const float* W; int base, N;
        if (idx < 65536)       { W = W1; base = 0;      N = 256; }
        else if (idx < 131072) { W = W2; base = 65536;  N = 256; }
        else                   { W = W3; base = 131072; N = 128; }
        int loc = idx - base;
        int nn = loc >> 8;   // K = 256
        int k = loc & 255;
        Wt[idx] = f2bf(W[(size_t)k * N + nn]);
    }
}

// ---------- scans ----------
__global__ void k_scan1(const int* __restrict__ cnt, int n, int* __restrict__ incl,
                        int* __restrict__ bsum) {
    __shared__ int sm[256];
    int t = threadIdx.x;
    int i = blockIdx.x * 256 + t;
    int v = (i < n) ? cnt[i] : 0;
    sm[t] = v; __syncthreads();
    for (int off = 1; off < 256; off <<= 1) {
        int add = (t >= off) ? sm[t - off] : 0;
        __syncthreads();
        sm[t] += add;
        __syncthreads();
    }
    if (i < n) incl[i] = sm[t];
    if (t == 255) bsum[blockIdx.x] = sm[255];
}

// fused scan2+scan3: block-local bsum prefix, inclusive->exclusive, dinv.
__global__ void k_scan23(const int* __restrict__ cnt, int n,
                         const int* __restrict__ bsum,
                         int* __restrict__ rs, float* __restrict__ dinv) {
    __shared__ int red[256];
    int t = threadIdx.x;
    int acc = 0;
    for (int j = t; j < (int)blockIdx.x; j += 256) acc += bsum[j];
    red[t] = acc; __syncthreads();
    for (int s = 128; s > 0; s >>= 1) {
        if (t < s) red[t] += red[t + s];
        __syncthreads();
    }
    int boff = red[0];
    int i = blockIdx.x * 256 + t;
    if (i < n) {
        int c = cnt[i];
        rs[i] = rs[i] + boff - c;
        dinv[i] = rsqrtf((float)(c + 1));  // +1 self loop
    }
}

// ---------- scatter (atomic-free; position = rs[dst] + seq) ----------
// standalone at full occupancy: rs[dst[e]] is a latency-bound random gather
__global__ void k_scatter2(const int* __restrict__ src, const int* __restrict__ dst,
                           const int* __restrict__ seq, int E,
                           const int* __restrict__ rs, int* __restrict__ col) {
    int e = blockIdx.x * 256 + threadIdx.x;
    if (e < E) col[rs[dst[e]] + seq[e]] = src[e];
}

// ---------- GEMM (R3-proven config: 128x128, single-buffer, lb(256,4)) ----------
__launch_bounds__(256, 4)
__global__ void k_gemm(const unsigned short* __restrict__ A,
                       const unsigned short* __restrict__ Wt,
                       unsigned short* __restrict__ Hs,
                       const float* __restrict__ dinv, int n, int N) {
    __shared__ unsigned short sA[128 * 32];
    __shared__ unsigned short sB[128 * 32];
    const int t = threadIdx.x;
    const int lane = t & 63;
    const int wave = t >> 6;
    const int wm = wave >> 1, wn = wave & 1;
    const int m0 = blockIdx.x * 128;
    const int n0 = blockIdx.y * 128;

    v4f acc[4][4];
#pragma unroll
    for (int i = 0; i < 4; i++)
#pragma unroll
        for (int j = 0; j < 4; j++)
#pragma unroll
            for (int r = 0; r < 4; r++) acc[i][j][r] = 0.f;

    const int c0 = t, c1 = t + 256;
    const int r0 = c0 >> 2, kc0 = (c0 & 3) * 8;
    const int r1 = c1 >> 2, kc1 = (c1 & 3) * 8;
    const size_t aBase0 = (size_t)(m0 + r0) * 256 + kc0;
    const size_t aBase1 = (size_t)(m0 + r1) * 256 + kc1;
    const size_t bBase0 = (size_t)(n0 + r0) * 256 + kc0;
    const size_t bBase1 = (size_t)(n0 + r1) * 256 + kc1;

    const int q = lane >> 4;
    const int lm = lane & 15;

    for (int k0 = 0; k0 < 256; k0 += 32) {
        __syncthreads();
        gl_lds16(A + aBase0 + k0, &sA[c0 * 8]);
        gl_lds16(A + aBase1 + k0, &sA[c1 * 8]);
        gl_lds16(Wt + bBase0 + k0, &sB[c0 * 8]);
        gl_lds16(Wt + bBase1 + k0, &sB[c1 * 8]);
        __syncthreads();

        v8s afr[4], bfr[4];
#pragma unroll
        for (int i = 0; i < 4; i++) {
            int r = wm * 64 + i * 16 + lm;
            afr[i] = *(const v8s*)&sA[r * 32 + q * 8];
        }
#pragma unroll
        for (int j = 0; j < 4; j++) {
            int nn = wn * 64 + j * 16 + lm;
            bfr[j] = *(const v8s*)&sB[nn * 32 + q * 8];
        }
#pragma unroll
        for (int i = 0; i < 4; i++)
#pragma unroll
            for (int j = 0; j < 4; j++)
                acc[i][j] = __builtin_amdgcn_mfma_f32_16x16x32_bf16(afr[i], bfr[j],
                                                                    acc[i][j], 0, 0, 0);
    }

    // epilogue: C/D layout col=lane&15, row=(lane>>4)*4+reg
#pragma unroll
    for (int i = 0; i < 4; i++) {
        int mbase = m0 + wm * 64 + i * 16 + q * 4;
#pragma unroll
        for (int r = 0; r < 4; r++) {
            int m = mbase + r;
            float s = (m < n) ? dinv[m] : 0.f;
#pragma unroll
            for (int j = 0; j < 4; j++) {
                int colI = n0 + wn * 64 + j * 16 + lm;
                Hs[(size_t)m * N + colI] = f2bf(acc[i][j][r] * s);
            }
        }
    }
}

// ---------- GEMM layer 1: A = x fp32, converted in-register during staging ----------
// Kills the pre-pass x->bf16 materialization (saves 51+25.6 MB -> 51 MB read once).
// OOB rows (m >= n, last tile) clamp to row n-1; epilogue masks them via s=0.
__launch_bounds__(256, 4)
__global__ void k_gemm_x(const float* __restrict__ x,
                         const unsigned short* __restrict__ Wt,
                         unsigned short* __restrict__ Hs,
                         const float* __restrict__ dinv, int n, int N) {
    __shared__ unsigned short sA[128 * 32];
    __shared__ unsigned short sB[128 * 32];
    const int t = threadIdx.x;
    const int lane = t & 63;
    const int wave = t >> 6;
    const int wm = wave >> 1, wn = wave & 1;
    const int m0 = blockIdx.x * 128;
    const int n0 = blockIdx.y * 128;

    v4f acc[4][4];
#pragma unroll
    for (int i = 0; i < 4; i++)
#pragma unroll
        for (int j = 0; j < 4; j++)
#pragma unroll
            for (int r = 0; r < 4; r++) acc[i][j][r] = 0.f;

    const int c0 = t, c1 = t + 256;
    const int r0 = c0 >> 2, kc0 = (c0 & 3) * 8;
    const int r1 = c1 >> 2, kc1 = (c1 & 3) * 8;
    const int ra0 = min(m0 + r0, n - 1);          // clamp OOB rows
    const int ra1 = min(m0 + r1, n - 1);
    const float* ax0 = x + (size_t)ra0 * 256 + kc0;
    const float* ax1 = x + (size_t)ra1 * 256 + kc1;
    const size_t bBase0 = (size_t)(n0 + r0) * 256 + kc0;
    const size_t bBase1 = (size_t)(n0 + r1) * 256 + kc1;

    const int q = lane >> 4;
    const int lm = lane & 15;

    for (int k0 = 0; k0 < 256; k0 += 32) {
        __syncthreads();
        // A: fp32 loads -> bf16 pack -> ds_write_b128 (lgkm); B: direct-to-LDS (vm)
        float4 u0 = *(const float4*)(ax0 + k0);
        float4 u1 = *(const float4*)(ax0 + k0 + 4);
        float4 u2 = *(const float4*)(ax1 + k0);
        float4 u3 = *(const float4*)(ax1 + k0 + 4);
        gl_lds16(Wt + bBase0 + k0, &sB[c0 * 8]);
        gl_lds16(Wt + bBase1 + k0, &sB[c1 * 8]);
        v8s w0, w1;
        w0[0] = (short)f2bf(u0.x); w0[1] = (short)f2bf(u0.y);
        w0[2] = (short)f2bf(u0.z); w0[3] = (short)f2bf(u0.w);
        w0[4] = (short)f2bf(u1.x); w0[5] = (short)f2bf(u1.y);
        w0[6] = (short)f2bf(u1.z); w0[7] = (short)f2bf(u1.w);
        w1[0] = (short)f2bf(u2.x); w1[1] = (short)f2bf(u2.y);
        w1[2] = (short)f2bf(u2.z); w1[3] = (short)f2bf(u2.w);
        w1[4] = (short)f2bf(u3.x); w1[5] = (short)f2bf(u3.y);
        w1[6] = (short)f2bf(u3.z); w1[7] = (short)f2bf(u3.w);
        *(v8s*)&sA[c0 * 8] = w0;
        *(v8s*)&sA[c1 * 8] = w1;
        __syncthreads();

        v8s afr[4], bfr[4];
#pragma unroll
        for (int i = 0; i < 4; i++) {
            int r = wm * 64 + i * 16 + lm;
            afr[i] = *(const v8s*)&sA[r * 32 + q * 8];
        }
#pragma unroll
        for (int j = 0; j < 4; j++) {
            int nn = wn * 64 + j * 16 + lm;
            bfr[j] = *(const v8s*)&sB[nn * 32 + q * 8];
        }
#pragma unroll
        for (int i = 0; i < 4; i++)
#pragma unroll
            for (int j = 0; j < 4; j++)
                acc[i][j] = __builtin_amdgcn_mfma_f32_16x16x32_bf16(afr[i], bfr[j],
                                                                    acc[i][j], 0, 0, 0);
    }

#pragma unroll
    for (int i = 0; i < 4; i++) {
        int mbase = m0 + wm * 64 + i * 16 + q * 4;
#pragma unroll
        for (int r = 0; r < 4; r++) {
            int m = mbase + r;
            float s = (m < n) ? dinv[m] : 0.f;
#pragma unroll
            for (int j = 0; j < 4; j++) {
                int colI = n0 + wn * 64 + j * 16 + lm;
                Hs[(size_t)m * N + colI] = f2bf(acc[i][j][r] * s);
            }
        }
    }
}

// ---------- aggregation: out[i] = act(dinv[i]*(sum_{nbr} hs[src] + hs[i]) + b) ----------
// (control group — random-gather memory-system ceiling; ILP-insensitive)
template <int D, bool RELU, bool F32OUT>
__launch_bounds__(256, 8)
__global__ void k_agg(const unsigned short* __restrict__ Hs,
                      const int* __restrict__ rs, const int* __restrict__ cnt,
                      const int* __restrict__ col, const float* __restrict__ dinv,
                      const float* __restrict__ bias,
                      unsigned short* __restrict__ outb, float* __restrict__ outf,
                      int n, int nzero) {
    constexpr int LPN = D / 8;     // lanes per neighbor row
    constexpr int NPG = 64 / LPN;  // neighbors per gather instruction
    const int lane = threadIdx.x & 63;
    const int i = blockIdx.x * 4 + (threadIdx.x >> 6);
    if (i >= n) return;
    const int g = lane / LPN;
    const int cl = lane % LPN;

    v2f acc[4];
#pragma unroll
    for (int k = 0; k < 4; k++) acc[k] = (v2f){0.f, 0.f};

    auto accq = [&](unsigned u, int k) {
        union { unsigned uu; float f; } lo, hi;
        lo.uu = u << 16;
        hi.uu = u & 0xffff0000u;
        v2f t; t[0] = lo.f; t[1] = hi.f;
        acc[k] += t;
    };
    auto acc16 = [&](uint4 q) { accq(q.x, 0); accq(q.y, 1); accq(q.z, 2); accq(q.w, 3); };

    const unsigned short* base = Hs + cl * 8;
    const int s = rs[i], deg = cnt[i];
    const int T = deg + 1;
    const int Tpad = (T + NPG - 1) & ~(NPG - 1);

    for (int b = 0; b < Tpad; b += 64) {
        int t = b + lane;
        int v;
        if (t == 0) v = i;
        else if (t <= deg) v = col[s + t - 1];
        else v = nzero;
        int lim = min(64, Tpad - b);
        int t2 = 0;
        for (; t2 + 4 * NPG <= lim; t2 += 4 * NPG) {
            int c0 = __shfl(v, t2 + 0 * NPG + g);
            int c1 = __shfl(v, t2 + 1 * NPG + g);
            int c2 = __shfl(v, t2 + 2 * NPG + g);
            int c3 = __shfl(v, t2 + 3 * NPG + g);
            uint4 q0 = *(const uint4*)(base + (size_t)c0 * D);
            uint4 q1 = *(const uint4*)(base + (size_t)c1 * D);
            uint4 q2 = *(const uint4*)(base + (size_t)c2 * D);
            uint4 q3 = *(const uint4*)(base + (size_t)c3 * D);
            acc16(q0); acc16(q1); acc16(q2); acc16(q3);
        }
        for (; t2 + NPG <= lim; t2 += NPG) {
            int c0 = __shfl(v, t2 + g);
            uint4 q0 = *(const uint4*)(base + (size_t)c0 * D);
            acc16(q0);
        }
    }

#pragma unroll
    for (int off = LPN; off < 64; off <<= 1) {
#pragma unroll
        for (int k = 0; k < 4; k++) {
            acc[k][0] += __shfl_xor(acc[k][0], off);
            acc[k][1] += __shfl_xor(acc[k][1], off);
        }
    }

    if (g == 0) {
        float di = dinv[i];
        float o[8];
#pragma unroll
        for (int k = 0; k < 4; k++) {
            o[2 * k + 0] = di * acc[k][0] + bias[cl * 8 + 2 * k + 0];
            o[2 * k + 1] = di * acc[k][1] + bias[cl * 8 + 2 * k + 1];
        }
        if (RELU) {
#pragma unroll
            for (int k = 0; k < 8; k++) o[k] = fmaxf(o[k], 0.f);
        }
        if constexpr (F32OUT) {
            float* p = outf + (size_t)i * D + cl * 8;
            *(float4*)p = make_float4(o[0], o[1], o[2], o[3]);
            *(float4*)(p + 4) = make_float4(o[4], o[5], o[6], o[7]);
        } else {
            uint4 q;
            q.x = ((unsigned)f2bf(o[1]) << 16) | f2bf(o[0]);
            q.y = ((unsigned)f2bf(o[3]) << 16) | f2bf(o[2]);
            q.z = ((unsigned)f2bf(o[5]) << 16) | f2bf(o[4]);
            q.w = ((unsigned)f2bf(o[7]) << 16) | f2bf(o[6]);
            *(uint4*)(outb + (size_t)i * D + cl * 8) = q;
        }
    }
}

// ---------- launch ----------
extern "C" void kernel_launch(void* const* d_in, const int* in_sizes, int n_in,
                              void* d_out, int out_size, void* d_ws, size_t ws_size,
                              hipStream_t stream) {
    const float* x  = (const float*)d_in[0];
    const int*   ei = (const int*)d_in[1];   // [2, E] int32
    const float* W1 = (const float*)d_in[2];
    const float* b1 = (const float*)d_in[3];
    const float* W2 = (const float*)d_in[4];
    const float* b2 = (const float*)d_in[5];
    const float* W3 = (const float*)d_in[6];
    const float* b3 = (const float*)d_in[7];

    const int n = in_sizes[0] / 256;     // 50000
    const int E = in_sizes[1] / 2;       // 800000
    const int mpad = ((n + 127) / 128) * 128;  // 50048

    char* ws = (char*)d_ws;
    size_t off = 0;
    auto alloc = [&](size_t bytes) -> void* {
        void* p = ws + off;
        off += (bytes + 255) & ~(size_t)255;
        return p;
    };
    int* cnt      = (int*)alloc((size_t)n * 4);
    int* rs       = (int*)alloc((size_t)n * 4);
    float* dinv   = (float*)alloc((size_t)n * 4);
    int* bsum     = (int*)alloc(256 * 4);
    int* seq      = (int*)alloc((size_t)E * 4);
    int* col      = (int*)alloc((size_t)E * 4);
    unsigned short* Wt = (unsigned short*)alloc((size_t)163840 * 2);
    unsigned short* W1t = Wt;
    unsigned short* W2t = Wt + 65536;
    unsigned short* W3t = Wt + 131072;
    unsigned short* bufA = (unsigned short*)alloc((size_t)mpad * 256 * 2);
    unsigned short* bufB = (unsigned short*)alloc((size_t)mpad * 256 * 2);
    (void)ws_size; (void)n_in; (void)out_size;

    const int* srcp = ei;
    const int* dstp = ei + E;
    const int gE = (E + 255) / 256;            // 3125
    const int gN = (n + 255) / 256;            // 196
    const int gW = 640;                        // 163840 / 256
    const int nmb = mpad / 128;                // 391

    hipMemsetAsync(cnt, 0, (size_t)n * 4, stream);

    k_pre1<<<gE + gW, 256, 0, stream>>>(dstp, E, cnt, seq, W1, W2, W3, Wt, gE);
    k_scan1<<<gN, 256, 0, stream>>>(cnt, n, rs, bsum);
    k_scan23<<<gN, 256, 0, stream>>>(cnt, n, bsum, rs, dinv);
    k_scatter2<<<gE, 256, 0, stream>>>(srcp, dstp, seq, E, rs, col);

    const int gAgg = (n + 3) / 4;
    dim3 gg1(nmb, 2);
    k_gemm_x<<<gg1, 256, 0, stream>>>(x, W1t, bufB, dinv, n, 256);
    k_agg<256, true, false><<<gAgg, 256, 0, stream>>>(bufB, rs, cnt, col, dinv, b1,
                                                      bufA, nullptr, n, n);
    k_gemm<<<gg1, 256, 0, stream>>>(bufA, W2t, bufB, dinv, n, 256);
    k_agg<256, true, false><<<gAgg, 256, 0, stream>>>(bufB, rs, cnt, col, dinv, b2,
                                                      bufA, nullptr, n, n);
    dim3 gg3(nmb, 1);
    k_gemm<<<gg3, 256, 0, stream>>>(bufA, W3t, bufB, dinv, n, 128);
    k_agg<128, false, true><<<gAgg, 256, 0, stream>>>(bufB, rs, cnt, col, dinv, b3,
                                                      nullptr, (float*)d_out, n, n);
}